// Round 10
// baseline (286.055 us; speedup 1.0000x reference)
//
#include <hip/hip_runtime.h>
#include <cstddef>
#include <cstdint>

#define BATCH 32
#define SEQ 2048
#define DM 1024

typedef __attribute__((ext_vector_type(8))) _Float16 half8v;
typedef __attribute__((ext_vector_type(4))) _Float16 half4v;
typedef __attribute__((ext_vector_type(4))) float f32x4;

// Persistent device-global scratch (fully rewritten every launch; no stale-state deps)
// g_Bpk: Wk_w pre-packed LDS-image: [nchunk 8][kt 32][kc 4][row 128][8 halfs] (2 MB)
__device__ _Float16 g_Bpk[8 * 32 * 4 * 128 * 8];
__device__ float g_q[BATCH * DM];              // q projection (128 KB)
__device__ float g_sp[16][BATCH * SEQ];        // scores partials: slot = nchunk*2 + wn

// tanh(x) = 1 - 2/(e^{2x}+1); saturates to +-1 correctly for |x| large
__device__ __forceinline__ float tanh_fast(float x) {
    float e = __expf(2.0f * x);
    return 1.0f - 2.0f / (e + 1.0f);
}

__device__ __forceinline__ void gload16(const void* g, void* l) {
    __builtin_amdgcn_global_load_lds((__attribute__((address_space(1))) void*)g,
                                     (__attribute__((address_space(3))) void*)l, 16, 0, 0);
}

// ---------------- pack Wk_w -> fp16 LDS-image layout (once per launch) ----------------
__global__ __launch_bounds__(256) void packb_kernel(const float* __restrict__ Wk_w) {
    int p = blockIdx.x;            // 0..255 = nc*32 + kt
    int nc = p >> 5, kt = p & 31;
    int t = threadIdx.x;
    int row = t >> 1, hh = t & 1;  // each thread: 2 kc planes of one row
    const float* src = Wk_w + (size_t)(nc * 128 + row) * DM + kt * 32;
#pragma unroll
    for (int i = 0; i < 2; ++i) {
        int kc = hh * 2 + i;
        float4 w0 = *reinterpret_cast<const float4*>(src + kc * 8);
        float4 w1 = *reinterpret_cast<const float4*>(src + kc * 8 + 4);
        union { _Float16 f[8]; half8v v; } h;
        h.f[0] = (_Float16)w0.x; h.f[1] = (_Float16)w0.y;
        h.f[2] = (_Float16)w0.z; h.f[3] = (_Float16)w0.w;
        h.f[4] = (_Float16)w1.x; h.f[5] = (_Float16)w1.y;
        h.f[6] = (_Float16)w1.z; h.f[7] = (_Float16)w1.w;
        *reinterpret_cast<half8v*>(
            &g_Bpk[((((size_t)p) * 4 + kc) * 128 + row) * 8]) = h.v;
    }
}

// ---------------- init: zero context (atomically accumulated) ----------------
__global__ __launch_bounds__(256) void init_kernel(float* __restrict__ context) {
    int idx = blockIdx.x * 256 + threadIdx.x;
    if (idx < BATCH * DM) context[idx] = 0.f;
}

// ---------------- q projection: block per output d; Wq read once total ----------------
__global__ __launch_bounds__(256) void qproj_kernel(const float* __restrict__ query,
                                                    const float* __restrict__ Wq_w,
                                                    const float* __restrict__ Wq_b) {
    int d = blockIdx.x;
    int t = threadIdx.x;
    __shared__ float wrow[DM];
    __shared__ float part[8][32];
    reinterpret_cast<float4*>(wrow)[t] =
        reinterpret_cast<const float4*>(Wq_w + (size_t)d * DM)[t];
    __syncthreads();
    int b = t & 31, seg = t >> 5;
    const float4* qp = reinterpret_cast<const float4*>(query + b * DM + seg * 128);
    const float4* wp = reinterpret_cast<const float4*>(wrow + seg * 128);
    float acc = 0.f;
#pragma unroll
    for (int i = 0; i < 32; ++i) {
        float4 qv = qp[i];
        float4 wv = wp[i];
        acc += qv.x * wv.x + qv.y * wv.y + qv.z * wv.z + qv.w * wv.w;
    }
    part[seg][b] = acc;
    __syncthreads();
    if (t < 32) {
        float s = Wq_b[d];
#pragma unroll
        for (int g = 0; g < 8; ++g) s += part[g][t];
        g_q[t * DM + d] = s;
    }
}

// ---------------- scores: fp16 MFMA GEMM, 64x64 wave tile, 3 blocks/CU ----------
#define BM 128
#define BN 128
#define BK 32
#define NT (DM / BK)   // 32 K-steps

// 64 AGPR acc + ~100 VGPR ~= 164 regs -> fits 3 waves/SIMD (budget 170).
__global__ __launch_bounds__(256, 3) void scores_kernel(const float* __restrict__ keys,
                                                        const float* __restrict__ Wk_b,
                                                        const float* __restrict__ v_w) {
    // kc-plane pad (129 rows): plane stride 2064 B = 516 dwords = 4-bank rotate
    // -> frag ds_read_b128 conflict-free. DMA issues stay within one plane
    // (64 contiguous rows), so the pad never breaks global_load_lds linearity.
    __shared__ _Float16 AhS[2][4][BM + 1][8];   // 16.5 KB
    __shared__ _Float16 BhS[2][4][BN + 1][8];   // 16.5 KB

    // XCD-aware order: 4096 blocks = 8 XCDs x 512 slots (bijective); nchunk-minor
    // so the 8 blocks sharing an A-tile are adjacent slots on one XCD.
    const unsigned bid = blockIdx.x;
    const unsigned L = (bid & 7u) * 512u + (bid >> 3);
    const int mtile = (int)(L >> 3);       // 0..511
    const int nchunk = (int)(L & 7u);      // 0..7
    const int m0 = mtile * BM;
    const int n0 = nchunk * BN;
    const int b = m0 >> 11;

    const int t = threadIdx.x;
    const int w = t >> 6, l = t & 63;
    const int wm = w >> 1, wn = w & 1;     // 2x2 waves; wave tile 64m x 64n
    const int lr = l & 15, lg = l >> 4;

    // A staging: wave w owns rows w*32..+31; inst j reads 8 full 128B row-segments
    // (lane -> row l>>3, col (l&7)*4).
    const int acol = (l & 7) * 4;
    const int akc = (l & 7) >> 1;          // 0..3
    const int aoff = ((l & 7) & 1) * 4;    // 0 or 4
    const float* Ap = keys + (size_t)(m0 + w * 32 + (l >> 3)) * DM + acol;

    // B DMA: wave w fetches kc=w plane; lane l -> contiguous 16B at base + l*16.
    const _Float16* Bp = g_Bpk + ((((size_t)nchunk * 32) * 4 + w) * 128 + l) * 8;

    float4 as[4];            // 1-deep A staging (16 VGPR)

    f32x4 acc[4][4];
#pragma unroll
    for (int mi = 0; mi < 4; ++mi)
#pragma unroll
        for (int ni = 0; ni < 4; ++ni)
#pragma unroll
            for (int c = 0; c < 4; ++c) acc[mi][ni][c] = 0.f;

#define LOAD_A(kt)                                                               \
    {                                                                            \
        _Pragma("unroll") for (int j = 0; j < 4; ++j)                            \
            as[j] = *reinterpret_cast<const float4*>(                            \
                Ap + (size_t)j * 8 * DM + (kt) * BK);                            \
    }
    // wave w DMAs kc=w plane: 2 issues x (64 rows x 16B contiguous)
#define ISSUE_B(kt, bufi)                                                        \
    {                                                                            \
        const _Float16* gb = Bp + (size_t)(kt) * (4 * 128 * 8);                  \
        _Pragma("unroll") for (int rg = 0; rg < 2; ++rg)                         \
            gload16(gb + rg * 512, &BhS[bufi][w][rg * 64][0]);                   \
    }
#define STAGE_A(bufi)                                                            \
    {                                                                            \
        _Pragma("unroll") for (int j = 0; j < 4; ++j) {                          \
            const float* fa = reinterpret_cast<const float*>(&as[j]);            \
            union { _Float16 f[4]; half4v v; } h;                                \
            h.f[0] = (_Float16)fa[0]; h.f[1] = (_Float16)fa[1];                  \
            h.f[2] = (_Float16)fa[2]; h.f[3] = (_Float16)fa[3];                  \
            *reinterpret_cast<half4v*>(                                          \
                &AhS[bufi][akc][w * 32 + j * 8 + (l >> 3)][aoff]) = h.v;         \
        }                                                                        \
    }
#define COMPUTE(bufi)                                                            \
    {                                                                            \
        half8v bhv[4];                                                           \
        _Pragma("unroll") for (int ni = 0; ni < 4; ++ni)                         \
            bhv[ni] = *reinterpret_cast<const half8v*>(                          \
                &BhS[bufi][lg][wn * 64 + ni * 16 + lr][0]);                      \
        __builtin_amdgcn_s_setprio(1);                                           \
        _Pragma("unroll") for (int mi = 0; mi < 4; ++mi) {                       \
            half8v ahv = *reinterpret_cast<const half8v*>(                       \
                &AhS[bufi][lg][wm * 64 + mi * 16 + lr][0]);                      \
            _Pragma("unroll") for (int ni = 0; ni < 4; ++ni)                     \
                acc[mi][ni] = __builtin_amdgcn_mfma_f32_16x16x32_f16(            \
                    ahv, bhv[ni], acc[mi][ni], 0, 0, 0);                         \
        }                                                                        \
        __builtin_amdgcn_s_setprio(0);                                          \
    }

    // ---- prologue: tile 0 staged; A(1) issued ----
    LOAD_A(0);
    ISSUE_B(0, 0);
    STAGE_A(0);                 // compiler waits on as regs
    LOAD_A(1);
    __syncthreads();            // drains B(0) DMA + A writes

    // ---- main loop: ONE barrier per step. Issue next-B early (hides under
    // COMPUTE); cvt+write next-A after COMPUTE (T14); issue A(t+2) last.
    int cur = 0;
    for (int tt = 0; tt < NT; ++tt) {
        if (tt + 1 < NT) ISSUE_B(tt + 1, cur ^ 1);
        COMPUTE(cur);
        if (tt + 1 < NT) STAGE_A(cur ^ 1);
        if (tt + 2 < NT) LOAD_A(tt + 2);
        __syncthreads();
        cur ^= 1;
    }

    // epilogue: tanh * v_w, reduce over this wave's 64 n-cols.
    // Slot = nchunk*2 + wn: exactly ONE writer per (slot,row) -> deterministic.
    float qb[4], vw[4];
#pragma unroll
    for (int ni = 0; ni < 4; ++ni) {
        int n = n0 + wn * 64 + ni * 16 + lr;
        qb[ni] = g_q[b * DM + n] + Wk_b[n];
        vw[ni] = v_w[n];
    }
#pragma unroll
    for (int mi = 0; mi < 4; ++mi) {
#pragma unroll
        for (int rg = 0; rg < 4; ++rg) {
            float p = 0.f;
#pragma unroll
            for (int ni = 0; ni < 4; ++ni) {
                float val = acc[mi][ni][rg] + qb[ni];
                p += tanh_fast(val) * vw[ni];
            }
#pragma unroll
            for (int off = 8; off >= 1; off >>= 1) p += __shfl_xor(p, off, 16);
            if (lr == 0)
                g_sp[nchunk * 2 + wn][m0 + wm * 64 + mi * 16 + lg * 4 + rg] = p;
        }
    }
#undef LOAD_A
#undef ISSUE_B
#undef STAGE_A
#undef COMPUTE
}

// ---------------- softmax over S per batch row (sums the 16 partial slots) --------
__global__ __launch_bounds__(256) void softmax_kernel(float* __restrict__ attn) {
    int b = blockIdx.x;
    int tid = threadIdx.x;
    __shared__ float redm[4];
    __shared__ float reds[4];
    float v[8];
    float mx = -1e30f;
#pragma unroll
    for (int i = 0; i < 8; ++i) {
        int idx = b * SEQ + i * 256 + tid;
        float s = 0.f;
#pragma unroll
        for (int pslot = 0; pslot < 16; ++pslot) s += g_sp[pslot][idx];
        v[i] = s;
        mx = fmaxf(mx, v[i]);
    }
#pragma unroll
    for (int off = 32; off >= 1; off >>= 1) mx = fmaxf(mx, __shfl_xor(mx, off));
    int wid = tid >> 6;
    if ((tid & 63) == 0) redm[wid] = mx;
    __syncthreads();
    mx = fmaxf(fmaxf(redm[0], redm[1]), fmaxf(redm[2], redm[3]));
    float sum = 0.f;
#pragma unroll
    for (int i = 0; i < 8; ++i) {
        v[i] = expf(v[i] - mx);
        sum += v[i];
    }
#pragma unroll
    for (int off = 32; off >= 1; off >>= 1) sum += __shfl_xor(sum, off);
    if ((tid & 63) == 0) reds[wid] = sum;
    __syncthreads();
    sum = reds[0] + reds[1] + reds[2] + reds[3];
    float inv = 1.f / sum;
#pragma unroll
    for (int i = 0; i < 8; ++i) attn[b * SEQ + i * 256 + tid] = v[i] * inv;
}

// ---------------- context = attn @ keys (coalesced float4 rows) ----------------
__global__ __launch_bounds__(256) void context_kernel(const float* __restrict__ keys,
                                                      const float* __restrict__ attn,
                                                      float* __restrict__ context) {
    int id = blockIdx.x;              // 32 b x 16 schunk = 512 blocks
    int schunk = id & 15;
    int b = id >> 4;
    int tid = threadIdx.x;
    __shared__ float a_s[128];
    if (tid < 128) a_s[tid] = attn[b * SEQ + schunk * 128 + tid];
    __syncthreads();
    const float4* kp =
        reinterpret_cast<const float4*>(keys + ((size_t)b * SEQ + schunk * 128) * DM) + tid;
    float4 acc = {0.f, 0.f, 0.f, 0.f};
#pragma unroll 4
    for (int s = 0; s < 128; ++s) {
        float4 kv = kp[(size_t)s * (DM / 4)];
        float a = a_s[s];
        acc.x += a * kv.x; acc.y += a * kv.y; acc.z += a * kv.z; acc.w += a * kv.w;
    }
    atomicAdd(&context[b * DM + tid * 4 + 0], acc.x);
    atomicAdd(&context[b * DM + tid * 4 + 1], acc.y);
    atomicAdd(&context[b * DM + tid * 4 + 2], acc.z);
    atomicAdd(&context[b * DM + tid * 4 + 3], acc.w);
}

extern "C" void kernel_launch(void* const* d_in, const int* in_sizes, int n_in,
                              void* d_out, int out_size, void* d_ws, size_t ws_size,
                              hipStream_t stream) {
    const float* query = (const float*)d_in[0];
    const float* keys  = (const float*)d_in[1];
    const float* Wq_w  = (const float*)d_in[2];
    const float* Wq_b  = (const float*)d_in[3];
    const float* Wk_w  = (const float*)d_in[4];
    const float* Wk_b  = (const float*)d_in[5];
    const float* v_w   = (const float*)d_in[6];
    // d_in[7] = v_b: additive constant on all scores -> cancels exactly in softmax.

    float* context = (float*)d_out;              // [32][1024]
    float* attn    = context + BATCH * DM;       // [32][2048]

    hipLaunchKernelGGL(packb_kernel, dim3(256), dim3(256), 0, stream, Wk_w);
    hipLaunchKernelGGL(init_kernel, dim3(128), dim3(256), 0, stream, context);
    hipLaunchKernelGGL(qproj_kernel, dim3(DM), dim3(256), 0, stream, query, Wq_w, Wq_b);
    hipLaunchKernelGGL(scores_kernel, dim3((BATCH * SEQ / BM) * (DM / BN)), dim3(256), 0, stream,
                       keys, Wk_b, v_w);
    hipLaunchKernelGGL(softmax_kernel, dim3(BATCH), dim3(256), 0, stream, attn);
    hipLaunchKernelGGL(context_kernel, dim3(512), dim3(256), 0, stream, keys, attn, context);
}

// Round 11
// 271.707 us; speedup vs baseline: 1.0528x; 1.0528x over previous
//
#include <hip/hip_runtime.h>
#include <cstddef>
#include <cstdint>

#define BATCH 32
#define SEQ 2048
#define DM 1024

typedef __attribute__((ext_vector_type(8))) _Float16 half8v;
typedef __attribute__((ext_vector_type(4))) _Float16 half4v;
typedef __attribute__((ext_vector_type(4))) float f32x4;

// Persistent device-global scratch (fully rewritten every launch)
// g_Bpk: Wk_w fp16 in FRAGMENT order [nc 8][sub 8][kt 32][kgrp 4][row 16][e 8] (2 MB).
// A wave's B-frag read is then ONE contiguous 1024B global_load_dwordx4 (lane l -> l*16B).
__device__ _Float16 g_Bpk[8 * 8 * 32 * 4 * 16 * 8];
__device__ float g_q[BATCH * DM];              // q projection (128 KB)
__device__ float g_sp[16][BATCH * SEQ];        // scores partials: slot = nchunk*2 + wn

// tanh(x) = 1 - 2/(e^{2x}+1); saturates to +-1 correctly for |x| large
__device__ __forceinline__ float tanh_fast(float x) {
    float e = __expf(2.0f * x);
    return 1.0f - 2.0f / (e + 1.0f);
}

// ---------------- pack Wk_w -> fp16 fragment-major layout (once, ~4 MB) ----------------
__global__ __launch_bounds__(256) void packb_kernel(const float* __restrict__ Wk_w) {
    int blk = blockIdx.x;              // 0..63 = nc*8 + sub
    int nc = blk >> 3, sub = blk & 7;
    int t = threadIdx.x;
    int row = t & 15, kgrp = (t >> 4) & 3, kt0 = t >> 6;   // kt0: 0..3
    const float* src = Wk_w + (size_t)(nc * 128 + sub * 16 + row) * DM;
    _Float16* dst = g_Bpk + (size_t)blk * 16384;           // block-local [kt][kgrp][row][8]
#pragma unroll
    for (int pass = 0; pass < 8; ++pass) {
        int kt = pass * 4 + kt0;
        float4 w0 = *reinterpret_cast<const float4*>(src + kt * 32 + kgrp * 8);
        float4 w1 = *reinterpret_cast<const float4*>(src + kt * 32 + kgrp * 8 + 4);
        union { _Float16 f[8]; half8v v; } h;
        h.f[0] = (_Float16)w0.x; h.f[1] = (_Float16)w0.y;
        h.f[2] = (_Float16)w0.z; h.f[3] = (_Float16)w0.w;
        h.f[4] = (_Float16)w1.x; h.f[5] = (_Float16)w1.y;
        h.f[6] = (_Float16)w1.z; h.f[7] = (_Float16)w1.w;
        *reinterpret_cast<half8v*>(&dst[(size_t)((kt * 4 + kgrp) * 16 + row) * 8]) = h.v;
    }
}

// ---------------- init: zero context (atomically accumulated) ----------------
__global__ __launch_bounds__(256) void init_kernel(float* __restrict__ context) {
    int idx = blockIdx.x * 256 + threadIdx.x;
    if (idx < BATCH * DM) context[idx] = 0.f;
}

// ---------------- q projection: block per output d; Wq read once total ----------------
__global__ __launch_bounds__(256) void qproj_kernel(const float* __restrict__ query,
                                                    const float* __restrict__ Wq_w,
                                                    const float* __restrict__ Wq_b) {
    int d = blockIdx.x;
    int t = threadIdx.x;
    __shared__ float wrow[DM];
    __shared__ float part[8][32];
    reinterpret_cast<float4*>(wrow)[t] =
        reinterpret_cast<const float4*>(Wq_w + (size_t)d * DM)[t];
    __syncthreads();
    int b = t & 31, seg = t >> 5;
    const float4* qp = reinterpret_cast<const float4*>(query + b * DM + seg * 128);
    const float4* wp = reinterpret_cast<const float4*>(wrow + seg * 128);
    float acc = 0.f;
#pragma unroll
    for (int i = 0; i < 32; ++i) {
        float4 qv = qp[i];
        float4 wv = wp[i];
        acc += qv.x * wv.x + qv.y * wv.y + qv.z * wv.z + qv.w * wv.w;
    }
    part[seg][b] = acc;
    __syncthreads();
    if (t < 32) {
        float s = Wq_b[d];
#pragma unroll
        for (int g = 0; g < 8; ++g) s += part[g][t];
        g_q[t * DM + d] = s;
    }
}

// ---------------- scores: fp16 MFMA GEMM; A via LDS, B-frags direct from L2 ----------
#define BM 128
#define BN 128
#define BK 32
#define NT (DM / BK)   // 32 K-steps

// Regs: acc 64 + A-stage 16 + B-frag 2x16 + addr/misc ~40 => ~150, fits 3 waves/SIMD.
__global__ __launch_bounds__(256, 3) void scores_kernel(const float* __restrict__ keys,
                                                        const float* __restrict__ Wk_b,
                                                        const float* __restrict__ v_w) {
    // A only in LDS now: kc-plane pad (129 rows) as in r9/r10.
    __shared__ _Float16 AhS[2][4][BM + 1][8];   // 16.5 KB total

    // XCD-aware order: 4096 blocks = 8 XCDs x 512 slots (bijective); nchunk-minor
    // so co-resident blocks share the A-panel (L1/L2 reuse).
    const unsigned bid = blockIdx.x;
    const unsigned L = (bid & 7u) * 512u + (bid >> 3);
    const int mtile = (int)(L >> 3);       // 0..511
    const int nchunk = (int)(L & 7u);      // 0..7
    const int m0 = mtile * BM;
    const int n0 = nchunk * BN;
    const int b = m0 >> 11;

    const int t = threadIdx.x;
    const int w = t >> 6, l = t & 63;
    const int wm = w >> 1, wn = w & 1;     // 2x2 waves; wave tile 64m x 64n
    const int lr = l & 15, lg = l >> 4;

    // A staging (proven r9/r10 pattern): 8 contiguous 128B row-segments per inst.
    const int akc = (l & 7) >> 1;          // 0..3
    const int aoff = ((l & 7) & 1) * 4;    // 0 or 4
    const float* Ap = keys + (size_t)(m0 + w * 32 + (l >> 3)) * DM + (l & 7) * 4;

    // B-frag base: lane l -> contiguous 16B of frag (kgrp=l>>4, row=l&15).
    // frag (ni) at sub = wn*4+ni: + ni*16384; K-step kt: + kt*512.
    const _Float16* Bp = g_Bpk + ((size_t)(nchunk * 8 + wn * 4)) * 16384
                               + (size_t)(l >> 4) * 128 + (size_t)(l & 15) * 8;

    float4 as[4];            // 1-deep A staging (16 VGPR)
    half8v bE[4], bO[4];     // B-frag double buffer (named: static indexing, rule #20)

    f32x4 acc[4][4];
#pragma unroll
    for (int mi = 0; mi < 4; ++mi)
#pragma unroll
        for (int ni = 0; ni < 4; ++ni)
#pragma unroll
            for (int c = 0; c < 4; ++c) acc[mi][ni][c] = 0.f;

#define LOAD_A(kt)                                                               \
    {                                                                            \
        _Pragma("unroll") for (int j = 0; j < 4; ++j)                            \
            as[j] = *reinterpret_cast<const float4*>(                            \
                Ap + (size_t)j * 8 * DM + (kt) * BK);                            \
    }
#define LOAD_BF(kt, dst)                                                         \
    {                                                                            \
        _Pragma("unroll") for (int ni = 0; ni < 4; ++ni)                         \
            dst[ni] = *reinterpret_cast<const half8v*>(                          \
                Bp + (size_t)ni * 16384 + (size_t)(kt) * 512);                   \
    }
#define STAGE_A(bufi)                                                            \
    {                                                                            \
        _Pragma("unroll") for (int j = 0; j < 4; ++j) {                          \
            const float* fa = reinterpret_cast<const float*>(&as[j]);            \
            union { _Float16 f[4]; half4v v; } h;                                \
            h.f[0] = (_Float16)fa[0]; h.f[1] = (_Float16)fa[1];                  \
            h.f[2] = (_Float16)fa[2]; h.f[3] = (_Float16)fa[3];                  \
            *reinterpret_cast<half4v*>(                                          \
                &AhS[bufi][akc][w * 32 + j * 8 + (l >> 3)][aoff]) = h.v;         \
        }                                                                        \
    }
#define COMPUTE(bufi, breg)                                                      \
    {                                                                            \
        __builtin_amdgcn_s_setprio(1);                                           \
        _Pragma("unroll") for (int mi = 0; mi < 4; ++mi) {                       \
            half8v ahv = *reinterpret_cast<const half8v*>(                       \
                &AhS[bufi][lg][wm * 64 + mi * 16 + lr][0]);                      \
            _Pragma("unroll") for (int ni = 0; ni < 4; ++ni)                     \
                acc[mi][ni] = __builtin_amdgcn_mfma_f32_16x16x32_f16(            \
                    ahv, breg[ni], acc[mi][ni], 0, 0, 0);                        \
        }                                                                        \
        __builtin_amdgcn_s_setprio(0);                                          \
    }

    // ---- prologue: A(0) staged into buf0; A(1) in regs; B(0) in bE ----
    LOAD_A(0);
    STAGE_A(0);                 // compiler waits on as regs
    LOAD_A(1);
    LOAD_BF(0, bE);
    __syncthreads();            // A(0) writes visible

    // ---- main loop, 2x unrolled; ONE barrier per step ----
    for (int tt = 0; tt + 1 < NT; tt += 2) {
        LOAD_BF(tt + 1, bO);                 // prefetch B(t+1) -> regs
        COMPUTE(0, bE);                      // tile tt from buf0 + bE
        STAGE_A(1);                          // A(tt+1) regs -> buf1
        if (tt + 2 < NT) LOAD_A(tt + 2);
        __syncthreads();

        if (tt + 2 < NT) LOAD_BF(tt + 2, bE);
        COMPUTE(1, bO);                      // tile tt+1 from buf1 + bO
        if (tt + 2 < NT) STAGE_A(0);         // A(tt+2) -> buf0
        if (tt + 3 < NT) LOAD_A(tt + 3);
        __syncthreads();
    }

    // epilogue: tanh * v_w, reduce over this wave's 64 n-cols.
    // Slot = nchunk*2 + wn: exactly ONE writer per (slot,row) -> deterministic.
    float qb[4], vw[4];
#pragma unroll
    for (int ni = 0; ni < 4; ++ni) {
        int n = n0 + wn * 64 + ni * 16 + lr;
        qb[ni] = g_q[b * DM + n] + Wk_b[n];
        vw[ni] = v_w[n];
    }
#pragma unroll
    for (int mi = 0; mi < 4; ++mi) {
#pragma unroll
        for (int rg = 0; rg < 4; ++rg) {
            float p = 0.f;
#pragma unroll
            for (int ni = 0; ni < 4; ++ni) {
                float val = acc[mi][ni][rg] + qb[ni];
                p += tanh_fast(val) * vw[ni];
            }
#pragma unroll
            for (int off = 8; off >= 1; off >>= 1) p += __shfl_xor(p, off, 16);
            if (lr == 0)
                g_sp[nchunk * 2 + wn][m0 + wm * 64 + mi * 16 + lg * 4 + rg] = p;
        }
    }
#undef LOAD_A
#undef LOAD_BF
#undef STAGE_A
#undef COMPUTE
}

// ---------------- softmax over S per batch row (sums the 16 partial slots) --------
__global__ __launch_bounds__(256) void softmax_kernel(float* __restrict__ attn) {
    int b = blockIdx.x;
    int tid = threadIdx.x;
    __shared__ float redm[4];
    __shared__ float reds[4];
    float v[8];
    float mx = -1e30f;
#pragma unroll
    for (int i = 0; i < 8; ++i) {
        int idx = b * SEQ + i * 256 + tid;
        float s = 0.f;
#pragma unroll
        for (int pslot = 0; pslot < 16; ++pslot) s += g_sp[pslot][idx];
        v[i] = s;
        mx = fmaxf(mx, v[i]);
    }
#pragma unroll
    for (int off = 32; off >= 1; off >>= 1) mx = fmaxf(mx, __shfl_xor(mx, off));
    int wid = tid >> 6;
    if ((tid & 63) == 0) redm[wid] = mx;
    __syncthreads();
    mx = fmaxf(fmaxf(redm[0], redm[1]), fmaxf(redm[2], redm[3]));
    float sum = 0.f;
#pragma unroll
    for (int i = 0; i < 8; ++i) {
        v[i] = expf(v[i] - mx);
        sum += v[i];
    }
#pragma unroll
    for (int off = 32; off >= 1; off >>= 1) sum += __shfl_xor(sum, off);
    if ((tid & 63) == 0) reds[wid] = sum;
    __syncthreads();
    sum = reds[0] + reds[1] + reds[2] + reds[3];
    float inv = 1.f / sum;
#pragma unroll
    for (int i = 0; i < 8; ++i) attn[b * SEQ + i * 256 + tid] = v[i] * inv;
}

// ---------------- context = attn @ keys (coalesced float4 rows) ----------------
__global__ __launch_bounds__(256) void context_kernel(const float* __restrict__ keys,
                                                      const float* __restrict__ attn,
                                                      float* __restrict__ context) {
    int id = blockIdx.x;              // 32 b x 16 schunk = 512 blocks
    int schunk = id & 15;
    int b = id >> 4;
    int tid = threadIdx.x;
    __shared__ float a_s[128];
    if (tid < 128) a_s[tid] = attn[b * SEQ + schunk * 128 + tid];
    __syncthreads();
    const float4* kp =
        reinterpret_cast<const float4*>(keys + ((size_t)b * SEQ + schunk * 128) * DM) + tid;
    float4 acc = {0.f, 0.f, 0.f, 0.f};
#pragma unroll 4
    for (int s = 0; s < 128; ++s) {
        float4 kv = kp[(size_t)s * (DM / 4)];
        float a = a_s[s];
        acc.x += a * kv.x; acc.y += a * kv.y; acc.z += a * kv.z; acc.w += a * kv.w;
    }
    atomicAdd(&context[b * DM + tid * 4 + 0], acc.x);
    atomicAdd(&context[b * DM + tid * 4 + 1], acc.y);
    atomicAdd(&context[b * DM + tid * 4 + 2], acc.z);
    atomicAdd(&context[b * DM + tid * 4 + 3], acc.w);
}

extern "C" void kernel_launch(void* const* d_in, const int* in_sizes, int n_in,
                              void* d_out, int out_size, void* d_ws, size_t ws_size,
                              hipStream_t stream) {
    const float* query = (const float*)d_in[0];
    const float* keys  = (const float*)d_in[1];
    const float* Wq_w  = (const float*)d_in[2];
    const float* Wq_b  = (const float*)d_in[3];
    const float* Wk_w  = (const float*)d_in[4];
    const float* Wk_b  = (const float*)d_in[5];
    const float* v_w   = (const float*)d_in[6];
    // d_in[7] = v_b: additive constant on all scores -> cancels exactly in softmax.

    float* context = (float*)d_out;              // [32][1024]
    float* attn    = context + BATCH * DM;       // [32][2048]

    hipLaunchKernelGGL(packb_kernel, dim3(64), dim3(256), 0, stream, Wk_w);
    hipLaunchKernelGGL(init_kernel, dim3(128), dim3(256), 0, stream, context);
    hipLaunchKernelGGL(qproj_kernel, dim3(DM), dim3(256), 0, stream, query, Wq_w, Wq_b);
    hipLaunchKernelGGL(scores_kernel, dim3((BATCH * SEQ / BM) * (DM / BN)), dim3(256), 0, stream,
                       keys, Wk_b, v_w);
    hipLaunchKernelGGL(softmax_kernel, dim3(BATCH), dim3(256), 0, stream, attn);
    hipLaunchKernelGGL(context_kernel, dim3(512), dim3(256), 0, stream, keys, attn, context);
}

// Round 13
// 270.080 us; speedup vs baseline: 1.0591x; 1.0060x over previous
//
#include <hip/hip_runtime.h>
#include <cstddef>
#include <cstdint>

#define BATCH 32
#define SEQ 2048
#define DM 1024

typedef __attribute__((ext_vector_type(8))) _Float16 half8v;
typedef __attribute__((ext_vector_type(4))) _Float16 half4v;
typedef __attribute__((ext_vector_type(2))) __fp16 fp16x2;   // cvt_pkrtz native type
typedef __attribute__((ext_vector_type(4))) float f32x4;

// Persistent device-global scratch (fully rewritten every launch)
// g_Bpk: Wk_w fp16 in FRAGMENT order [nc 8][sub 8][kt 32][kgrp 4][row 16][e 8] (2 MB).
__device__ _Float16 g_Bpk[8 * 8 * 32 * 4 * 16 * 8];
__device__ float g_q[BATCH * DM];              // q projection (128 KB)
__device__ float g_sp[16][BATCH * SEQ];        // scores partials: slot = nchunk*2 + wn

// tanh(x) = 1 - 2/(e^{2x}+1); saturates to +-1 correctly for |x| large
__device__ __forceinline__ float tanh_fast(float x) {
    float e = __expf(2.0f * x);
    return 1.0f - 2.0f / (e + 1.0f);
}

// ---------------- pack Wk_w -> fp16 fragment-major layout (once, ~4 MB) ----------------
__global__ __launch_bounds__(256) void packb_kernel(const float* __restrict__ Wk_w) {
    int blk = blockIdx.x;              // 0..63 = nc*8 + sub
    int nc = blk >> 3, sub = blk & 7;
    int t = threadIdx.x;
    int row = t & 15, kgrp = (t >> 4) & 3, kt0 = t >> 6;   // kt0: 0..3
    const float* src = Wk_w + (size_t)(nc * 128 + sub * 16 + row) * DM;
    _Float16* dst = g_Bpk + (size_t)blk * 16384;           // block-local [kt][kgrp][row][8]
#pragma unroll
    for (int pass = 0; pass < 8; ++pass) {
        int kt = pass * 4 + kt0;
        float4 w0 = *reinterpret_cast<const float4*>(src + kt * 32 + kgrp * 8);
        float4 w1 = *reinterpret_cast<const float4*>(src + kt * 32 + kgrp * 8 + 4);
        union { _Float16 f[8]; half8v v; } h;
        h.f[0] = (_Float16)w0.x; h.f[1] = (_Float16)w0.y;
        h.f[2] = (_Float16)w0.z; h.f[3] = (_Float16)w0.w;
        h.f[4] = (_Float16)w1.x; h.f[5] = (_Float16)w1.y;
        h.f[6] = (_Float16)w1.z; h.f[7] = (_Float16)w1.w;
        *reinterpret_cast<half8v*>(&dst[(size_t)((kt * 4 + kgrp) * 16 + row) * 8]) = h.v;
    }
}

// ---------------- init: zero context (atomically accumulated) ----------------
__global__ __launch_bounds__(256) void init_kernel(float* __restrict__ context) {
    int idx = blockIdx.x * 256 + threadIdx.x;
    if (idx < BATCH * DM) context[idx] = 0.f;
}

// ---------------- q projection: block per output d; Wq read once total ----------------
__global__ __launch_bounds__(256) void qproj_kernel(const float* __restrict__ query,
                                                    const float* __restrict__ Wq_w,
                                                    const float* __restrict__ Wq_b) {
    int d = blockIdx.x;
    int t = threadIdx.x;
    __shared__ float wrow[DM];
    __shared__ float part[8][32];
    reinterpret_cast<float4*>(wrow)[t] =
        reinterpret_cast<const float4*>(Wq_w + (size_t)d * DM)[t];
    __syncthreads();
    int b = t & 31, seg = t >> 5;
    const float4* qp = reinterpret_cast<const float4*>(query + b * DM + seg * 128);
    const float4* wp = reinterpret_cast<const float4*>(wrow + seg * 128);
    float acc = 0.f;
#pragma unroll
    for (int i = 0; i < 32; ++i) {
        float4 qv = qp[i];
        float4 wv = wp[i];
        acc += qv.x * wv.x + qv.y * wv.y + qv.z * wv.z + qv.w * wv.w;
    }
    part[seg][b] = acc;
    __syncthreads();
    if (t < 32) {
        float s = Wq_b[d];
#pragma unroll
        for (int g = 0; g < 8; ++g) s += part[g][t];
        g_q[t * DM + d] = s;
    }
}

// ---------------- scores: fp16 MFMA GEMM; A via LDS, B-frags from L2; barrier-ride ----
#define BM 128
#define BN 128
#define BK 32
#define NT (DM / BK)   // 32 K-steps

// Regs: acc 64 AGPR + A-stage 2x16 + B-frag 2x16 + addr/misc ~35 => ~164 unified,
// fits 3 waves/SIMD (budget 170). If WRITE_SIZE explodes -> spilled -> revert to 2.
__global__ __launch_bounds__(256, 3) void scores_kernel(const float* __restrict__ keys,
                                                        const float* __restrict__ Wk_b,
                                                        const float* __restrict__ v_w) {
    // A only in LDS: kc-plane pad (129 rows).
    __shared__ _Float16 AhS[2][4][BM + 1][8];   // 16.5 KB total

    // XCD-aware order: 4096 blocks = 8 XCDs x 512 slots (bijective); nchunk-minor
    // so co-resident blocks share the A-panel (L1/L2 reuse).
    const unsigned bid = blockIdx.x;
    const unsigned L = (bid & 7u) * 512u + (bid >> 3);
    const int mtile = (int)(L >> 3);       // 0..511
    const int nchunk = (int)(L & 7u);      // 0..7
    const int m0 = mtile * BM;
    const int n0 = nchunk * BN;
    const int b = m0 >> 11;

    const int t = threadIdx.x;
    const int w = t >> 6, l = t & 63;
    const int wm = w >> 1, wn = w & 1;     // 2x2 waves; wave tile 64m x 64n
    const int lr = l & 15, lg = l >> 4;

    // A staging: 8 contiguous 128B row-segments per inst.
    const int akc = (l & 7) >> 1;          // 0..3
    const int aoff = ((l & 7) & 1) * 4;    // 0 or 4
    const float* Ap = keys + (size_t)(m0 + w * 32 + (l >> 3)) * DM + (l & 7) * 4;

    // B-frag base: lane l -> contiguous 16B of frag (kgrp=l>>4, row=l&15).
    const _Float16* Bp = g_Bpk + ((size_t)(nchunk * 8 + wn * 4)) * 16384
                               + (size_t)(l >> 4) * 128 + (size_t)(l & 15) * 8;

    float4 asE[4], asO[4];   // A staging double buffer (named: static idx, rule #20)
    half8v bE[4], bO[4];     // B-frag double buffer

    f32x4 acc[4][4];
#pragma unroll
    for (int mi = 0; mi < 4; ++mi)
#pragma unroll
        for (int ni = 0; ni < 4; ++ni)
#pragma unroll
            for (int c = 0; c < 4; ++c) acc[mi][ni][c] = 0.f;

#define LOAD_A(kt, dst)                                                          \
    {                                                                            \
        _Pragma("unroll") for (int j = 0; j < 4; ++j)                            \
            dst[j] = *reinterpret_cast<const float4*>(                           \
                Ap + (size_t)j * 8 * DM + (kt) * BK);                            \
    }
#define LOAD_BF(kt, dst)                                                         \
    {                                                                            \
        _Pragma("unroll") for (int ni = 0; ni < 4; ++ni)                         \
            dst[ni] = *reinterpret_cast<const half8v*>(                          \
                Bp + (size_t)ni * 16384 + (size_t)(kt) * 512);                   \
    }
#define STAGE_A(bufi, areg)                                                      \
    {                                                                            \
        _Pragma("unroll") for (int j = 0; j < 4; ++j) {                          \
            const float* fa = reinterpret_cast<const float*>(&areg[j]);          \
            union { fp16x2 h2[2]; half4v v; } u;                                 \
            u.h2[0] = __builtin_amdgcn_cvt_pkrtz(fa[0], fa[1]);                  \
            u.h2[1] = __builtin_amdgcn_cvt_pkrtz(fa[2], fa[3]);                  \
            *reinterpret_cast<half4v*>(                                          \
                &AhS[bufi][akc][w * 32 + j * 8 + (l >> 3)][aoff]) = u.v;         \
        }                                                                        \
    }
#define COMPUTE(bufi, breg)                                                      \
    {                                                                            \
        __builtin_amdgcn_s_setprio(1);                                           \
        _Pragma("unroll") for (int mi = 0; mi < 4; ++mi) {                       \
            half8v ahv = *reinterpret_cast<const half8v*>(                       \
                &AhS[bufi][lg][wm * 64 + mi * 16 + lr][0]);                      \
            _Pragma("unroll") for (int ni = 0; ni < 4; ++ni)                     \
                acc[mi][ni] = __builtin_amdgcn_mfma_f32_16x16x32_f16(            \
                    ahv, breg[ni], acc[mi][ni], 0, 0, 0);                        \
        }                                                                        \
        __builtin_amdgcn_s_setprio(0);                                          \
    }
    // LDS hazards only need lgkmcnt; global loads RIDE the barrier (compiler's
    // scoreboard inserts counted vmcnt before each register use).
#define SYNC()                                                                   \
    asm volatile("s_waitcnt lgkmcnt(0)" ::: "memory");                           \
    __builtin_amdgcn_s_barrier();                                                \
    asm volatile("" ::: "memory");

    // ---- prologue: A(0)->buf0, B(0)->bE, A(1)->asO in flight ----
    LOAD_A(0, asE);
    LOAD_BF(0, bE);
    STAGE_A(0, asE);            // scoreboard waits asE
    LOAD_A(1, asO);
    SYNC()

    // ---- main loop, 2x unrolled; ONE lgkm-only barrier per step ----
    for (int tt = 0; tt < NT; tt += 2) {
        // even tile tt: compute buf0+bE; stage A(tt+1); prefetch B(tt+1), A(tt+2)
        LOAD_BF(tt + 1, bO);                 // tt+1 <= 31 always (NT even)
        if (tt + 2 < NT) LOAD_A(tt + 2, asE);
        COMPUTE(0, bE);
        STAGE_A(1, asO);
        SYNC()

        // odd tile tt+1: compute buf1+bO; stage A(tt+2); prefetch B(tt+2), A(tt+3)
        if (tt + 2 < NT) LOAD_BF(tt + 2, bE);
        if (tt + 3 < NT) LOAD_A(tt + 3, asO);
        COMPUTE(1, bO);
        if (tt + 2 < NT) STAGE_A(0, asE);
        SYNC()
    }

    // epilogue: tanh * v_w, reduce over this wave's 64 n-cols.
    // Slot = nchunk*2 + wn: exactly ONE writer per (slot,row) -> deterministic.
    float qb[4], vw[4];
#pragma unroll
    for (int ni = 0; ni < 4; ++ni) {
        int n = n0 + wn * 64 + ni * 16 + lr;
        qb[ni] = g_q[b * DM + n] + Wk_b[n];
        vw[ni] = v_w[n];
    }
#pragma unroll
    for (int mi = 0; mi < 4; ++mi) {
#pragma unroll
        for (int rg = 0; rg < 4; ++rg) {
            float p = 0.f;
#pragma unroll
            for (int ni = 0; ni < 4; ++ni) {
                float val = acc[mi][ni][rg] + qb[ni];
                p += tanh_fast(val) * vw[ni];
            }
#pragma unroll
            for (int off = 8; off >= 1; off >>= 1) p += __shfl_xor(p, off, 16);
            if (lr == 0)
                g_sp[nchunk * 2 + wn][m0 + wm * 64 + mi * 16 + lg * 4 + rg] = p;
        }
    }
#undef LOAD_A
#undef LOAD_BF
#undef STAGE_A
#undef COMPUTE
#undef SYNC
}

// ---------------- softmax over S per batch row (sums the 16 partial slots) --------
__global__ __launch_bounds__(256) void softmax_kernel(float* __restrict__ attn) {
    int b = blockIdx.x;
    int tid = threadIdx.x;
    __shared__ float redm[4];
    __shared__ float reds[4];
    float v[8];
    float mx = -1e30f;
#pragma unroll
    for (int i = 0; i < 8; ++i) {
        int idx = b * SEQ + i * 256 + tid;
        float s = 0.f;
#pragma unroll
        for (int pslot = 0; pslot < 16; ++pslot) s += g_sp[pslot][idx];
        v[i] = s;
        mx = fmaxf(mx, v[i]);
    }
#pragma unroll
    for (int off = 32; off >= 1; off >>= 1) mx = fmaxf(mx, __shfl_xor(mx, off));
    int wid = tid >> 6;
    if ((tid & 63) == 0) redm[wid] = mx;
    __syncthreads();
    mx = fmaxf(fmaxf(redm[0], redm[1]), fmaxf(redm[2], redm[3]));
    float sum = 0.f;
#pragma unroll
    for (int i = 0; i < 8; ++i) {
        v[i] = expf(v[i] - mx);
        sum += v[i];
    }
#pragma unroll
    for (int off = 32; off >= 1; off >>= 1) sum += __shfl_xor(sum, off);
    if ((tid & 63) == 0) reds[wid] = sum;
    __syncthreads();
    sum = reds[0] + reds[1] + reds[2] + reds[3];
    float inv = 1.f / sum;
#pragma unroll
    for (int i = 0; i < 8; ++i) attn[b * SEQ + i * 256 + tid] = v[i] * inv;
}

// ---------------- context = attn @ keys (coalesced float4 rows) ----------------
__global__ __launch_bounds__(256) void context_kernel(const float* __restrict__ keys,
                                                      const float* __restrict__ attn,
                                                      float* __restrict__ context) {
    int id = blockIdx.x;              // 32 b x 16 schunk = 512 blocks
    int schunk = id & 15;
    int b = id >> 4;
    int tid = threadIdx.x;
    __shared__ float a_s[128];
    if (tid < 128) a_s[tid] = attn[b * SEQ + schunk * 128 + tid];
    __syncthreads();
    const float4* kp =
        reinterpret_cast<const float4*>(keys + ((size_t)b * SEQ + schunk * 128) * DM) + tid;
    float4 acc = {0.f, 0.f, 0.f, 0.f};
#pragma unroll 4
    for (int s = 0; s < 128; ++s) {
        float4 kv = kp[(size_t)s * (DM / 4)];
        float a = a_s[s];
        acc.x += a * kv.x; acc.y += a * kv.y; acc.z += a * kv.z; acc.w += a * kv.w;
    }
    atomicAdd(&context[b * DM + tid * 4 + 0], acc.x);
    atomicAdd(&context[b * DM + tid * 4 + 1], acc.y);
    atomicAdd(&context[b * DM + tid * 4 + 2], acc.z);
    atomicAdd(&context[b * DM + tid * 4 + 3], acc.w);
}

extern "C" void kernel_launch(void* const* d_in, const int* in_sizes, int n_in,
                              void* d_out, int out_size, void* d_ws, size_t ws_size,
                              hipStream_t stream) {
    const float* query = (const float*)d_in[0];
    const float* keys  = (const float*)d_in[1];
    const float* Wq_w  = (const float*)d_in[2];
    const float* Wq_b  = (const float*)d_in[3];
    const float* Wk_w  = (const float*)d_in[4];
    const float* Wk_b  = (const float*)d_in[5];
    const float* v_w   = (const float*)d_in[6];
    // d_in[7] = v_b: additive constant on all scores -> cancels exactly in softmax.

    float* context = (float*)d_out;              // [32][1024]
    float* attn    = context + BATCH * DM;       // [32][2048]

    hipLaunchKernelGGL(packb_kernel, dim3(64), dim3(256), 0, stream, Wk_w);
    hipLaunchKernelGGL(init_kernel, dim3(128), dim3(256), 0, stream, context);
    hipLaunchKernelGGL(qproj_kernel, dim3(DM), dim3(256), 0, stream, query, Wq_w, Wq_b);
    hipLaunchKernelGGL(scores_kernel, dim3((BATCH * SEQ / BM) * (DM / BN)), dim3(256), 0, stream,
                       keys, Wk_b, v_w);
    hipLaunchKernelGGL(softmax_kernel, dim3(BATCH), dim3(256), 0, stream, attn);
    hipLaunchKernelGGL(context_kernel, dim3(512), dim3(256), 0, stream, keys, attn, context);
}

// Round 14
// 255.728 us; speedup vs baseline: 1.1186x; 1.0561x over previous
//
#include <hip/hip_runtime.h>
#include <cstddef>
#include <cstdint>

#define BATCH 32
#define SEQ 2048
#define DM 1024

typedef __attribute__((ext_vector_type(8))) _Float16 half8v;
typedef __attribute__((ext_vector_type(4))) _Float16 half4v;
typedef __attribute__((ext_vector_type(2))) __fp16 fp16x2;   // cvt_pkrtz native type
typedef __attribute__((ext_vector_type(4))) float f32x4;

// Persistent device-global scratch (fully rewritten every launch)
// g_Bpk: Wk_w fp16 in FRAGMENT order [nc 8][sub 8][kt 32][kgrp 4][row 16][e 8] (2 MB).
__device__ _Float16 g_Bpk[8 * 8 * 32 * 4 * 16 * 8];
__device__ float g_q[BATCH * DM];              // q projection (128 KB)
__device__ float g_sp[16][BATCH * SEQ];        // scores partials: slot = nchunk*2 + wn

// tanh(x) = 1 - 2/(e^{2x}+1); saturates to +-1 correctly for |x| large
__device__ __forceinline__ float tanh_fast(float x) {
    float e = __expf(2.0f * x);
    return 1.0f - 2.0f / (e + 1.0f);
}

// ---------------- pack Wk_w -> fp16 fragment-major layout (once, ~4 MB) ----------------
__global__ __launch_bounds__(256) void packb_kernel(const float* __restrict__ Wk_w) {
    int blk = blockIdx.x;              // 0..63 = nc*8 + sub
    int nc = blk >> 3, sub = blk & 7;
    int t = threadIdx.x;
    int row = t & 15, kgrp = (t >> 4) & 3, kt0 = t >> 6;   // kt0: 0..3
    const float* src = Wk_w + (size_t)(nc * 128 + sub * 16 + row) * DM;
    _Float16* dst = g_Bpk + (size_t)blk * 16384;           // block-local [kt][kgrp][row][8]
#pragma unroll
    for (int pass = 0; pass < 8; ++pass) {
        int kt = pass * 4 + kt0;
        float4 w0 = *reinterpret_cast<const float4*>(src + kt * 32 + kgrp * 8);
        float4 w1 = *reinterpret_cast<const float4*>(src + kt * 32 + kgrp * 8 + 4);
        union { _Float16 f[8]; half8v v; } h;
        h.f[0] = (_Float16)w0.x; h.f[1] = (_Float16)w0.y;
        h.f[2] = (_Float16)w0.z; h.f[3] = (_Float16)w0.w;
        h.f[4] = (_Float16)w1.x; h.f[5] = (_Float16)w1.y;
        h.f[6] = (_Float16)w1.z; h.f[7] = (_Float16)w1.w;
        *reinterpret_cast<half8v*>(&dst[(size_t)((kt * 4 + kgrp) * 16 + row) * 8]) = h.v;
    }
}

// ---------------- init: zero context (atomically accumulated) ----------------
__global__ __launch_bounds__(256) void init_kernel(float* __restrict__ context) {
    int idx = blockIdx.x * 256 + threadIdx.x;
    if (idx < BATCH * DM) context[idx] = 0.f;
}

// ---------------- q projection: block per output d; Wq read once total ----------------
__global__ __launch_bounds__(256) void qproj_kernel(const float* __restrict__ query,
                                                    const float* __restrict__ Wq_w,
                                                    const float* __restrict__ Wq_b) {
    int d = blockIdx.x;
    int t = threadIdx.x;
    __shared__ float wrow[DM];
    __shared__ float part[8][32];
    reinterpret_cast<float4*>(wrow)[t] =
        reinterpret_cast<const float4*>(Wq_w + (size_t)d * DM)[t];
    __syncthreads();
    int b = t & 31, seg = t >> 5;
    const float4* qp = reinterpret_cast<const float4*>(query + b * DM + seg * 128);
    const float4* wp = reinterpret_cast<const float4*>(wrow + seg * 128);
    float acc = 0.f;
#pragma unroll
    for (int i = 0; i < 32; ++i) {
        float4 qv = qp[i];
        float4 wv = wp[i];
        acc += qv.x * wv.x + qv.y * wv.y + qv.z * wv.z + qv.w * wv.w;
    }
    part[seg][b] = acc;
    __syncthreads();
    if (t < 32) {
        float s = Wq_b[d];
#pragma unroll
        for (int g = 0; g < 8; ++g) s += part[g][t];
        g_q[t * DM + d] = s;
    }
}

// ---------------- scores: fp16 MFMA GEMM; K-tile=64, 2 sub-steps, 1 barrier/64K ------
#define BM 128
#define BN 128
#define NT2 16   // 16 K-tiles of 64 (= 32 sub-tiles of 32)

// Regs: acc 64 AGPR + A-stage 32 + B-frag 32 + misc ~30 => ~158 unified <= 170
// at 3 waves/SIMD. WRITE_SIZE is the spill tripwire (r7: spill -> GBs of scratch).
__global__ __launch_bounds__(256, 3) void scores_kernel(const float* __restrict__ keys,
                                                        const float* __restrict__ Wk_b,
                                                        const float* __restrict__ v_w) {
    // A in LDS: [dbuf][sub][kc 4][129 rows][8] fp16; kc-plane pad (129) = 4-bank
    // rotate, conflict-free frag reads. 33 KB -> 3 blocks = 99 KB/CU.
    __shared__ _Float16 AhS[2][2][4][BM + 1][8];

    // XCD-aware order: 4096 blocks = 8 XCDs x 512 slots (bijective); nchunk-minor
    // so co-resident blocks share the A-panel (L2 reuse: A read from HBM ~once).
    const unsigned bid = blockIdx.x;
    const unsigned L = (bid & 7u) * 512u + (bid >> 3);
    const int mtile = (int)(L >> 3);       // 0..511
    const int nchunk = (int)(L & 7u);      // 0..7
    const int m0 = mtile * BM;
    const int n0 = nchunk * BN;
    const int b = m0 >> 11;

    const int t = threadIdx.x;
    const int w = t >> 6, l = t & 63;
    const int wm = w >> 1, wn = w & 1;     // 2x2 waves; wave tile 64m x 64n
    const int lr = l & 15, lg = l >> 4;

    // A staging: 8 contiguous 128B row-segments per inst (proven r9-r13 pattern).
    const int akc = (l & 7) >> 1;          // 0..3
    const int aoff = ((l & 7) & 1) * 4;    // 0 or 4
    const float* Ap = keys + (size_t)(m0 + w * 32 + (l >> 3)) * DM + (l & 7) * 4;

    // B-frag base: lane l -> contiguous 16B of frag (kgrp=l>>4, row=l&15).
    const _Float16* Bp = g_Bpk + ((size_t)(nchunk * 8 + wn * 4)) * 16384
                               + (size_t)(l >> 4) * 128 + (size_t)(l & 15) * 8;

    float4 as0[4], as1[4];   // A staging: the two 32-K subs of the NEXT K-tile
    half8v bE[4], bO[4];     // B-frags: bE = sub0, bO = sub1 (named: rule #20)

    f32x4 acc[4][4];
#pragma unroll
    for (int mi = 0; mi < 4; ++mi)
#pragma unroll
        for (int ni = 0; ni < 4; ++ni)
#pragma unroll
            for (int c = 0; c < 4; ++c) acc[mi][ni][c] = 0.f;

    // kt = K-tile index (64-K units); ks = sub-tile index (32-K units)
#define LOAD_A2(kt)                                                              \
    {                                                                            \
        _Pragma("unroll") for (int j = 0; j < 4; ++j)                            \
            as0[j] = *reinterpret_cast<const float4*>(                           \
                Ap + (size_t)j * 8 * DM + (kt) * 64);                            \
        _Pragma("unroll") for (int j = 0; j < 4; ++j)                            \
            as1[j] = *reinterpret_cast<const float4*>(                           \
                Ap + (size_t)j * 8 * DM + (kt) * 64 + 32);                       \
    }
#define LOAD_BF(ks, dst)                                                         \
    {                                                                            \
        _Pragma("unroll") for (int ni = 0; ni < 4; ++ni)                         \
            dst[ni] = *reinterpret_cast<const half8v*>(                          \
                Bp + (size_t)ni * 16384 + (size_t)(ks) * 512);                   \
    }
#define STAGE_ONE(bufi, sub, areg)                                               \
    {                                                                            \
        _Pragma("unroll") for (int j = 0; j < 4; ++j) {                          \
            const float* fa = reinterpret_cast<const float*>(&areg[j]);          \
            union { fp16x2 h2[2]; half4v v; } u;                                 \
            u.h2[0] = __builtin_amdgcn_cvt_pkrtz(fa[0], fa[1]);                  \
            u.h2[1] = __builtin_amdgcn_cvt_pkrtz(fa[2], fa[3]);                  \
            *reinterpret_cast<half4v*>(                                          \
                &AhS[bufi][sub][akc][w * 32 + j * 8 + (l >> 3)][aoff]) = u.v;    \
        }                                                                        \
    }
#define COMPUTE_S(bufi, sub, breg)                                               \
    {                                                                            \
        __builtin_amdgcn_s_setprio(1);                                           \
        _Pragma("unroll") for (int mi = 0; mi < 4; ++mi) {                       \
            half8v ahv = *reinterpret_cast<const half8v*>(                       \
                &AhS[bufi][sub][lg][wm * 64 + mi * 16 + lr][0]);                 \
            _Pragma("unroll") for (int ni = 0; ni < 4; ++ni)                     \
                acc[mi][ni] = __builtin_amdgcn_mfma_f32_16x16x32_f16(            \
                    ahv, breg[ni], acc[mi][ni], 0, 0, 0);                        \
        }                                                                        \
        __builtin_amdgcn_s_setprio(0);                                          \
    }
    // LDS hazards only need lgkmcnt; global loads ride the barrier (compiler
    // scoreboard inserts counted vmcnt before each register use).
#define SYNC()                                                                   \
    asm volatile("s_waitcnt lgkmcnt(0)" ::: "memory");                           \
    __builtin_amdgcn_s_barrier();                                                \
    asm volatile("" ::: "memory");

    // ---- prologue: K-tile 0 -> buf0; B(sub0=0) -> bE ----
    LOAD_A2(0);
    LOAD_BF(0, bE);
    STAGE_ONE(0, 0, as0);       // scoreboard waits as regs
    STAGE_ONE(0, 1, as1);
    SYNC()

    // ---- main loop: one barrier per 64-K tile; 32 MFMA/wave per interval ----
    // Schedule per step tt (buf cb=tt&1):
    //   issue B(sub1) + A(next tile)  [latency hidden under sub0 compute]
    //   compute sub0 (bE), compute sub1 (bO)
    //   stage A(next) -> buf cb^1     [as regs ~800cy old; A-panel L2-hot]
    //   issue next tile's B(sub0) -> bE  [consumed ~300+cy later, post-barrier]
    for (int tt = 0; tt < NT2; ++tt) {
        const int cb = tt & 1;
        LOAD_BF(2 * tt + 1, bO);
        if (tt + 1 < NT2) LOAD_A2(tt + 1);
        COMPUTE_S(cb, 0, bE);
        COMPUTE_S(cb, 1, bO);
        if (tt + 1 < NT2) {
            STAGE_ONE(cb ^ 1, 0, as0);
            STAGE_ONE(cb ^ 1, 1, as1);
            LOAD_BF(2 * tt + 2, bE);
        }
        SYNC()
    }

    // epilogue: tanh * v_w, reduce over this wave's 64 n-cols.
    // Slot = nchunk*2 + wn: exactly ONE writer per (slot,row) -> deterministic.
    float qb[4], vw[4];
#pragma unroll
    for (int ni = 0; ni < 4; ++ni) {
        int n = n0 + wn * 64 + ni * 16 + lr;
        qb[ni] = g_q[b * DM + n] + Wk_b[n];
        vw[ni] = v_w[n];
    }
#pragma unroll
    for (int mi = 0; mi < 4; ++mi) {
#pragma unroll
        for (int rg = 0; rg < 4; ++rg) {
            float p = 0.f;
#pragma unroll
            for (int ni = 0; ni < 4; ++ni) {
                float val = acc[mi][ni][rg] + qb[ni];
                p += tanh_fast(val) * vw[ni];
            }
#pragma unroll
            for (int off = 8; off >= 1; off >>= 1) p += __shfl_xor(p, off, 16);
            if (lr == 0)
                g_sp[nchunk * 2 + wn][m0 + wm * 64 + mi * 16 + lg * 4 + rg] = p;
        }
    }
#undef LOAD_A2
#undef LOAD_BF
#undef STAGE_ONE
#undef COMPUTE_S
#undef SYNC
}

// ---------------- softmax over S per batch row (sums the 16 partial slots) --------
__global__ __launch_bounds__(256) void softmax_kernel(float* __restrict__ attn) {
    int b = blockIdx.x;
    int tid = threadIdx.x;
    __shared__ float redm[4];
    __shared__ float reds[4];
    float v[8];
    float mx = -1e30f;
#pragma unroll
    for (int i = 0; i < 8; ++i) {
        int idx = b * SEQ + i * 256 + tid;
        float s = 0.f;
#pragma unroll
        for (int pslot = 0; pslot < 16; ++pslot) s += g_sp[pslot][idx];
        v[i] = s;
        mx = fmaxf(mx, v[i]);
    }
#pragma unroll
    for (int off = 32; off >= 1; off >>= 1) mx = fmaxf(mx, __shfl_xor(mx, off));
    int wid = tid >> 6;
    if ((tid & 63) == 0) redm[wid] = mx;
    __syncthreads();
    mx = fmaxf(fmaxf(redm[0], redm[1]), fmaxf(redm[2], redm[3]));
    float sum = 0.f;
#pragma unroll
    for (int i = 0; i < 8; ++i) {
        v[i] = expf(v[i] - mx);
        sum += v[i];
    }
#pragma unroll
    for (int off = 32; off >= 1; off >>= 1) sum += __shfl_xor(sum, off);
    if ((tid & 63) == 0) reds[wid] = sum;
    __syncthreads();
    sum = reds[0] + reds[1] + reds[2] + reds[3];
    float inv = 1.f / sum;
#pragma unroll
    for (int i = 0; i < 8; ++i) attn[b * SEQ + i * 256 + tid] = v[i] * inv;
}

// ---------------- context = attn @ keys (coalesced float4 rows) ----------------
__global__ __launch_bounds__(256) void context_kernel(const float* __restrict__ keys,
                                                      const float* __restrict__ attn,
                                                      float* __restrict__ context) {
    int id = blockIdx.x;              // 32 b x 16 schunk = 512 blocks
    int schunk = id & 15;
    int b = id >> 4;
    int tid = threadIdx.x;
    __shared__ float a_s[128];
    if (tid < 128) a_s[tid] = attn[b * SEQ + schunk * 128 + tid];
    __syncthreads();
    const float4* kp =
        reinterpret_cast<const float4*>(keys + ((size_t)b * SEQ + schunk * 128) * DM) + tid;
    float4 acc = {0.f, 0.f, 0.f, 0.f};
#pragma unroll 4
    for (int s = 0; s < 128; ++s) {
        float4 kv = kp[(size_t)s * (DM / 4)];
        float a = a_s[s];
        acc.x += a * kv.x; acc.y += a * kv.y; acc.z += a * kv.z; acc.w += a * kv.w;
    }
    atomicAdd(&context[b * DM + tid * 4 + 0], acc.x);
    atomicAdd(&context[b * DM + tid * 4 + 1], acc.y);
    atomicAdd(&context[b * DM + tid * 4 + 2], acc.z);
    atomicAdd(&context[b * DM + tid * 4 + 3], acc.w);
}

extern "C" void kernel_launch(void* const* d_in, const int* in_sizes, int n_in,
                              void* d_out, int out_size, void* d_ws, size_t ws_size,
                              hipStream_t stream) {
    const float* query = (const float*)d_in[0];
    const float* keys  = (const float*)d_in[1];
    const float* Wq_w  = (const float*)d_in[2];
    const float* Wq_b  = (const float*)d_in[3];
    const float* Wk_w  = (const float*)d_in[4];
    const float* Wk_b  = (const float*)d_in[5];
    const float* v_w   = (const float*)d_in[6];
    // d_in[7] = v_b: additive constant on all scores -> cancels exactly in softmax.

    float* context = (float*)d_out;              // [32][1024]
    float* attn    = context + BATCH * DM;       // [32][2048]

    hipLaunchKernelGGL(packb_kernel, dim3(64), dim3(256), 0, stream, Wk_w);
    hipLaunchKernelGGL(init_kernel, dim3(128), dim3(256), 0, stream, context);
    hipLaunchKernelGGL(qproj_kernel, dim3(DM), dim3(256), 0, stream, query, Wq_w, Wq_b);
    hipLaunchKernelGGL(scores_kernel, dim3((BATCH * SEQ / BM) * (DM / BN)), dim3(256), 0, stream,
                       keys, Wk_b, v_w);
    hipLaunchKernelGGL(softmax_kernel, dim3(BATCH), dim3(256), 0, stream, attn);
    hipLaunchKernelGGL(context_kernel, dim3(512), dim3(256), 0, stream, keys, attn, context);
}